// Round 1
// baseline (3439.952 us; speedup 1.0000x reference)
//
#include <hip/hip_runtime.h>
#include <hip/hip_bf16.h>

#define NEG_SLOPE 0.01f
#define C 128
#define NGRAPH 64
#define BM 64
#define BN 64
#define BK 16

// monotone float <-> uint mapping for atomicMax-based segment max
__device__ __forceinline__ unsigned fmap(float x){
  unsigned b = __float_as_uint(x);
  return (b & 0x80000000u) ? ~b : (b | 0x80000000u);
}
__device__ __forceinline__ float funmap(unsigned k){
  return (k & 0x80000000u) ? __uint_as_float(k & 0x7FFFFFFFu) : __uint_as_float(~k);
}

__global__ void deg_kernel(const int* __restrict__ dst, float* __restrict__ deg, int E){
  int e = blockIdx.x * blockDim.x + threadIdx.x;
  if(e < E) atomicAdd(&deg[dst[e]], 1.0f);
}

__global__ void inv_kernel(float* deg, int N){
  int n = blockIdx.x * blockDim.x + threadIdx.x;
  if(n < N) deg[n] = 1.0f / fmaxf(deg[n], 1.0f);
}

// Bcat[0:128][:] = W_l, Bcat[128:256][:] = W_r  (both [128][128] row-major)
__global__ void pack_kernel(const float* __restrict__ Wl, const float* __restrict__ Wr,
                            float* __restrict__ Bcat){
  int i = blockIdx.x * blockDim.x + threadIdx.x;
  if(i < C*C) Bcat[i] = Wl[i];
  else if(i < 2*C*C) Bcat[i] = Wr[i - C*C];
}

// 32 threads per edge, float4 per thread: gather x[src] row, atomic scatter to agg[dst]
__global__ void aggregate_kernel(const float* __restrict__ xin, const int* __restrict__ src,
                                 const int* __restrict__ dst, float* __restrict__ agg, int E){
  long long idx = (long long)blockIdx.x * blockDim.x + threadIdx.x;
  int e = (int)(idx >> 5);
  if(e >= E) return;
  int c = ((int)idx & 31) << 2;
  int s = src[e], d = dst[e];
  const float4 v = *(const float4*)(xin + (long long)s * C + c);
  float* out = agg + (long long)d * C + c;
  atomicAdd(out + 0, v.x);
  atomicAdd(out + 1, v.y);
  atomicAdd(out + 2, v.z);
  atomicAdd(out + 3, v.w);
}

// h = leakyrelu( [agg*inv_deg | x] @ Bcat + bias ),  A: [M,256] virtual, Bcat: [256,128]
__global__ __launch_bounds__(256) void gemm_fused(
    const float* __restrict__ agg, const float* __restrict__ inv_deg,
    const float* __restrict__ xin, const float* __restrict__ Bcat,
    const float* __restrict__ bias, float* __restrict__ hout, int M)
{
  __shared__ float As[BK][BM + 1];
  __shared__ float Bs[BK][BN];
  int tid = threadIdx.x;
  int bm = blockIdx.y * BM;
  int bn = blockIdx.x * BN;
  int tx = tid & 15, ty = tid >> 4;
  float acc[4][4] = {{0.f}};
  int arow = tid >> 2, akq = (tid & 3) << 2;   // A loader: 64 rows x 16 k (float4)
  int brow = tid >> 4, bcol = (tid & 15) << 2; // B loader: 16 k x 64 cols (float4)

  for(int k0 = 0; k0 < 2 * C; k0 += BK){
    int grow = bm + arow;
    float4 av = make_float4(0.f, 0.f, 0.f, 0.f);
    if(grow < M){
      if(k0 < C){
        av = *(const float4*)(agg + (long long)grow * C + k0 + akq);
        float s = inv_deg[grow];
        av.x *= s; av.y *= s; av.z *= s; av.w *= s;
      }else{
        av = *(const float4*)(xin + (long long)grow * C + (k0 - C) + akq);
      }
    }
    As[akq + 0][arow] = av.x;
    As[akq + 1][arow] = av.y;
    As[akq + 2][arow] = av.z;
    As[akq + 3][arow] = av.w;
    *(float4*)&Bs[brow][bcol] = *(const float4*)(Bcat + (long long)(k0 + brow) * C + bn + bcol);
    __syncthreads();
#pragma unroll
    for(int k = 0; k < BK; k++){
      float a0 = As[k][ty*4+0], a1 = As[k][ty*4+1], a2 = As[k][ty*4+2], a3 = As[k][ty*4+3];
      float b0 = Bs[k][tx*4+0], b1 = Bs[k][tx*4+1], b2 = Bs[k][tx*4+2], b3 = Bs[k][tx*4+3];
      acc[0][0] += a0*b0; acc[0][1] += a0*b1; acc[0][2] += a0*b2; acc[0][3] += a0*b3;
      acc[1][0] += a1*b0; acc[1][1] += a1*b1; acc[1][2] += a1*b2; acc[1][3] += a1*b3;
      acc[2][0] += a2*b0; acc[2][1] += a2*b1; acc[2][2] += a2*b2; acc[2][3] += a2*b3;
      acc[3][0] += a3*b0; acc[3][1] += a3*b1; acc[3][2] += a3*b2; acc[3][3] += a3*b3;
    }
    __syncthreads();
  }
#pragma unroll
  for(int i = 0; i < 4; i++){
    int row = bm + ty*4 + i;
    if(row >= M) continue;
#pragma unroll
    for(int j = 0; j < 4; j++){
      int col = bn + tx*4 + j;
      float v = acc[i][j] + bias[col];
      v = v > 0.f ? v : NEG_SLOPE * v;
      hout[(long long)row * C + col] = v;
    }
  }
}

// batch is sorted: run local max per contiguous graph segment, flush with atomicMax
__global__ void pool_kernel(const float* __restrict__ h, const int* __restrict__ batch,
                            unsigned* __restrict__ pooled_u, int N){
  int f = threadIdx.x;            // 0..127 (feature)
  int n0 = blockIdx.x * 256;      // node tile
  int cur_g = -1;
  unsigned run = 0u;
  for(int i = 0; i < 256; i++){
    int n = n0 + i;
    if(n >= N) break;
    int g = batch[n];
    if(g != cur_g){
      if(cur_g >= 0) atomicMax(&pooled_u[cur_g * C + f], run);
      cur_g = g; run = 0u;
    }
    unsigned k = fmap(h[(long long)n * C + f]);
    run = run > k ? run : k;
  }
  if(cur_g >= 0) atomicMax(&pooled_u[cur_g * C + f], run);
}

__global__ void fc_kernel(const unsigned* __restrict__ pooled_u, const float* __restrict__ Wfc,
                          const float* __restrict__ bfc, float* __restrict__ out){
  int t = threadIdx.x;   // 0..127
  int g = t >> 1, o = t & 1;
  float s = bfc[o];
  for(int k = 0; k < C; k++)
    s += funmap(pooled_u[g * C + k]) * Wfc[k * 2 + o];
  out[g * 2 + o] = s;
}

extern "C" void kernel_launch(void* const* d_in, const int* in_sizes, int n_in,
                              void* d_out, int out_size, void* d_ws, size_t ws_size,
                              hipStream_t stream) {
  const float* x    = (const float*)d_in[0];
  const int*   ei   = (const int*)d_in[1];
  const int*   batch= (const int*)d_in[2];
  const float* W1l  = (const float*)d_in[3];
  const float* b1   = (const float*)d_in[4];
  const float* W1r  = (const float*)d_in[5];
  const float* W2l  = (const float*)d_in[6];
  const float* b2   = (const float*)d_in[7];
  const float* W2r  = (const float*)d_in[8];
  const float* W3l  = (const float*)d_in[9];
  const float* b3   = (const float*)d_in[10];
  const float* W3r  = (const float*)d_in[11];
  const float* Wfc  = (const float*)d_in[12];
  const float* bfc  = (const float*)d_in[13];
  float* out = (float*)d_out;

  const int N = in_sizes[0] / C;   // 50000
  const int E = in_sizes[1] / 2;   // 600000
  const int* srcv = ei;
  const int* dstv = ei + E;

  char* ws = (char*)d_ws;
  size_t off = 0;
  auto alloc = [&](size_t bytes) -> void* {
    void* p = ws + off;
    off += (bytes + 255) & ~(size_t)255;
    return p;
  };
  float*    deg    = (float*)alloc((size_t)N * 4);
  float*    agg    = (float*)alloc((size_t)N * C * 4);
  float*    hA     = (float*)alloc((size_t)N * C * 4);
  float*    hB     = (float*)alloc((size_t)N * C * 4);
  float*    B1     = (float*)alloc((size_t)2 * C * C * 4);
  float*    B2     = (float*)alloc((size_t)2 * C * C * 4);
  float*    B3     = (float*)alloc((size_t)2 * C * C * 4);
  unsigned* pooled = (unsigned*)alloc((size_t)NGRAPH * C * 4);

  hipMemsetAsync(deg, 0, (size_t)N * 4, stream);
  hipMemsetAsync(pooled, 0, (size_t)NGRAPH * C * 4, stream);
  deg_kernel<<<(E + 255) / 256, 256, 0, stream>>>(dstv, deg, E);
  inv_kernel<<<(N + 255) / 256, 256, 0, stream>>>(deg, N);
  pack_kernel<<<(2 * C * C + 255) / 256, 256, 0, stream>>>(W1l, W1r, B1);
  pack_kernel<<<(2 * C * C + 255) / 256, 256, 0, stream>>>(W2l, W2r, B2);
  pack_kernel<<<(2 * C * C + 255) / 256, 256, 0, stream>>>(W3l, W3r, B3);

  dim3 ggrid(C / BN, (N + BM - 1) / BM);
  long long aggthreads = (long long)E * 32;
  int aggblocks = (int)((aggthreads + 255) / 256);

  // layer 1
  hipMemsetAsync(agg, 0, (size_t)N * C * 4, stream);
  aggregate_kernel<<<aggblocks, 256, 0, stream>>>(x, srcv, dstv, agg, E);
  gemm_fused<<<ggrid, 256, 0, stream>>>(agg, deg, x, B1, b1, hA, N);
  // layer 2
  hipMemsetAsync(agg, 0, (size_t)N * C * 4, stream);
  aggregate_kernel<<<aggblocks, 256, 0, stream>>>(hA, srcv, dstv, agg, E);
  gemm_fused<<<ggrid, 256, 0, stream>>>(agg, deg, hA, B2, b2, hB, N);
  // layer 3
  hipMemsetAsync(agg, 0, (size_t)N * C * 4, stream);
  aggregate_kernel<<<aggblocks, 256, 0, stream>>>(hB, srcv, dstv, agg, E);
  gemm_fused<<<ggrid, 256, 0, stream>>>(agg, deg, hB, B3, b3, hA, N);

  pool_kernel<<<(N + 255) / 256, 128, 0, stream>>>(hA, batch, pooled, N);
  fc_kernel<<<1, 128, 0, stream>>>(pooled, Wfc, bfc, out);
}

// Round 2
// 648.809 us; speedup vs baseline: 5.3019x; 5.3019x over previous
//
#include <hip/hip_runtime.h>
#include <hip/hip_bf16.h>

#define NEG_SLOPE 0.01f
#define C 128
#define NGRAPH 64
#define BM 64
#define BN 64
#define BK 16

// monotone float <-> uint mapping for atomicMax-based segment max
__device__ __forceinline__ unsigned fmap(float x){
  unsigned b = __float_as_uint(x);
  return (b & 0x80000000u) ? ~b : (b | 0x80000000u);
}
__device__ __forceinline__ float funmap(unsigned k){
  return (k & 0x80000000u) ? __uint_as_float(k & 0x7FFFFFFFu) : __uint_as_float(~k);
}

// ---------- CSR build ----------
__global__ void deg_kernel(const int* __restrict__ dst, int* __restrict__ deg, int E){
  int e = blockIdx.x * blockDim.x + threadIdx.x;
  if(e < E) atomicAdd(&deg[dst[e]], 1);
}

__global__ void inv_kernel(const int* __restrict__ deg, float* __restrict__ inv_deg, int N){
  int n = blockIdx.x * blockDim.x + threadIdx.x;
  if(n < N) inv_deg[n] = 1.0f / fmaxf((float)deg[n], 1.0f);
}

// single-block exclusive scan over N (+ total at row_start[N])
__global__ void scan_kernel(const int* __restrict__ deg, int* __restrict__ row_start, int N){
  __shared__ int sm[1024];
  __shared__ int s_run;
  int t = threadIdx.x;
  if(t == 0) s_run = 0;
  __syncthreads();
  for(int base = 0; base < N; base += 1024){
    int v = (base + t < N) ? deg[base + t] : 0;
    sm[t] = v;
    __syncthreads();
    // inclusive Hillis-Steele
    for(int off = 1; off < 1024; off <<= 1){
      int add = (t >= off) ? sm[t - off] : 0;
      __syncthreads();
      sm[t] += add;
      __syncthreads();
    }
    int run = s_run;
    if(base + t < N) row_start[base + t] = run + sm[t] - v;   // exclusive
    __syncthreads();
    if(t == 0) s_run = run + sm[1023];
    __syncthreads();
  }
  if(t == 0) row_start[N] = s_run;
}

__global__ void csr_fill_kernel(const int* __restrict__ src, const int* __restrict__ dst,
                                const int* __restrict__ row_start, int* __restrict__ cursor,
                                int* __restrict__ csr, int E){
  int e = blockIdx.x * blockDim.x + threadIdx.x;
  if(e >= E) return;
  int d = dst[e];
  int p = atomicAdd(&cursor[d], 1);
  csr[row_start[d] + p] = src[e];
}

// ---------- aggregation: one wave per node, CSR gather-sum, write mean ----------
__global__ __launch_bounds__(256) void agg_csr_kernel(
    const float* __restrict__ xin, const int* __restrict__ csr,
    const int* __restrict__ row_start, const float* __restrict__ inv_deg,
    float* __restrict__ mean, int N)
{
  int node = blockIdx.x * (blockDim.x >> 6) + (threadIdx.x >> 6);
  if(node >= N) return;
  int lane = threadIdx.x & 63;
  int beg = row_start[node], end = row_start[node + 1];
  float2 acc = make_float2(0.f, 0.f);
  for(int base = beg; base < end; base += 64){
    int cnt = end - base; if(cnt > 64) cnt = 64;
    int s_l = (base + lane < end) ? csr[base + lane] : 0;
    for(int j = 0; j < cnt; j++){
      int s = __shfl(s_l, j, 64);
      float2 v = *(const float2*)(xin + (long long)s * C + lane * 2);
      acc.x += v.x; acc.y += v.y;
    }
  }
  float sc = inv_deg[node];
  *(float2*)(mean + (long long)node * C + lane * 2) = make_float2(acc.x * sc, acc.y * sc);
}

// Bcat[0:128][:] = W_l, Bcat[128:256][:] = W_r  (both [128][128] row-major)
__global__ void pack_kernel(const float* __restrict__ Wl, const float* __restrict__ Wr,
                            float* __restrict__ Bcat){
  int i = blockIdx.x * blockDim.x + threadIdx.x;
  if(i < C*C) Bcat[i] = Wl[i];
  else if(i < 2*C*C) Bcat[i] = Wr[i - C*C];
}

// h = leakyrelu( [mean | x] @ Bcat + bias ),  A: [M,256] virtual, Bcat: [256,128]
__global__ __launch_bounds__(256) void gemm_fused(
    const float* __restrict__ mean, const float* __restrict__ xin,
    const float* __restrict__ Bcat, const float* __restrict__ bias,
    float* __restrict__ hout, int M)
{
  __shared__ float As[BK][BM + 1];
  __shared__ float Bs[BK][BN];
  int tid = threadIdx.x;
  int bm = blockIdx.y * BM;
  int bn = blockIdx.x * BN;
  int tx = tid & 15, ty = tid >> 4;
  float acc[4][4] = {{0.f}};
  int arow = tid >> 2, akq = (tid & 3) << 2;   // A loader: 64 rows x 16 k (float4)
  int brow = tid >> 4, bcol = (tid & 15) << 2; // B loader: 16 k x 64 cols (float4)

  for(int k0 = 0; k0 < 2 * C; k0 += BK){
    int grow = bm + arow;
    float4 av = make_float4(0.f, 0.f, 0.f, 0.f);
    if(grow < M){
      const float* srcp = (k0 < C) ? (mean + (long long)grow * C + k0 + akq)
                                   : (xin  + (long long)grow * C + (k0 - C) + akq);
      av = *(const float4*)srcp;
    }
    As[akq + 0][arow] = av.x;
    As[akq + 1][arow] = av.y;
    As[akq + 2][arow] = av.z;
    As[akq + 3][arow] = av.w;
    *(float4*)&Bs[brow][bcol] = *(const float4*)(Bcat + (long long)(k0 + brow) * C + bn + bcol);
    __syncthreads();
#pragma unroll
    for(int k = 0; k < BK; k++){
      float a0 = As[k][ty*4+0], a1 = As[k][ty*4+1], a2 = As[k][ty*4+2], a3 = As[k][ty*4+3];
      float b0 = Bs[k][tx*4+0], b1 = Bs[k][tx*4+1], b2 = Bs[k][tx*4+2], b3 = Bs[k][tx*4+3];
      acc[0][0] += a0*b0; acc[0][1] += a0*b1; acc[0][2] += a0*b2; acc[0][3] += a0*b3;
      acc[1][0] += a1*b0; acc[1][1] += a1*b1; acc[1][2] += a1*b2; acc[1][3] += a1*b3;
      acc[2][0] += a2*b0; acc[2][1] += a2*b1; acc[2][2] += a2*b2; acc[2][3] += a2*b3;
      acc[3][0] += a3*b0; acc[3][1] += a3*b1; acc[3][2] += a3*b2; acc[3][3] += a3*b3;
    }
    __syncthreads();
  }
#pragma unroll
  for(int i = 0; i < 4; i++){
    int row = bm + ty*4 + i;
    if(row >= M) continue;
#pragma unroll
    for(int j = 0; j < 4; j++){
      int col = bn + tx*4 + j;
      float v = acc[i][j] + bias[col];
      v = v > 0.f ? v : NEG_SLOPE * v;
      hout[(long long)row * C + col] = v;
    }
  }
}

// batch is sorted: run local max per contiguous graph segment, flush with atomicMax
__global__ void pool_kernel(const float* __restrict__ h, const int* __restrict__ batch,
                            unsigned* __restrict__ pooled_u, int N){
  int f = threadIdx.x;            // 0..127 (feature)
  int n0 = blockIdx.x * 256;      // node tile
  int cur_g = -1;
  unsigned run = 0u;
  for(int i = 0; i < 256; i++){
    int n = n0 + i;
    if(n >= N) break;
    int g = batch[n];
    if(g != cur_g){
      if(cur_g >= 0) atomicMax(&pooled_u[cur_g * C + f], run);
      cur_g = g; run = 0u;
    }
    unsigned k = fmap(h[(long long)n * C + f]);
    run = run > k ? run : k;
  }
  if(cur_g >= 0) atomicMax(&pooled_u[cur_g * C + f], run);
}

__global__ void fc_kernel(const unsigned* __restrict__ pooled_u, const float* __restrict__ Wfc,
                          const float* __restrict__ bfc, float* __restrict__ out){
  int t = threadIdx.x;   // 0..127
  int g = t >> 1, o = t & 1;
  float s = bfc[o];
  for(int k = 0; k < C; k++)
    s += funmap(pooled_u[g * C + k]) * Wfc[k * 2 + o];
  out[g * 2 + o] = s;
}

extern "C" void kernel_launch(void* const* d_in, const int* in_sizes, int n_in,
                              void* d_out, int out_size, void* d_ws, size_t ws_size,
                              hipStream_t stream) {
  const float* x    = (const float*)d_in[0];
  const int*   ei   = (const int*)d_in[1];
  const int*   batch= (const int*)d_in[2];
  const float* W1l  = (const float*)d_in[3];
  const float* b1   = (const float*)d_in[4];
  const float* W1r  = (const float*)d_in[5];
  const float* W2l  = (const float*)d_in[6];
  const float* b2   = (const float*)d_in[7];
  const float* W2r  = (const float*)d_in[8];
  const float* W3l  = (const float*)d_in[9];
  const float* b3   = (const float*)d_in[10];
  const float* W3r  = (const float*)d_in[11];
  const float* Wfc  = (const float*)d_in[12];
  const float* bfc  = (const float*)d_in[13];
  float* out = (float*)d_out;

  const int N = in_sizes[0] / C;   // 50000
  const int E = in_sizes[1] / 2;   // 600000
  const int* srcv = ei;
  const int* dstv = ei + E;

  char* ws = (char*)d_ws;
  size_t off = 0;
  auto alloc = [&](size_t bytes) -> void* {
    void* p = ws + off;
    off += (bytes + 255) & ~(size_t)255;
    return p;
  };
  int*      deg    = (int*)alloc((size_t)N * 4);
  float*    inv_d  = (float*)alloc((size_t)N * 4);
  int*      rows   = (int*)alloc((size_t)(N + 1) * 4);
  int*      cursor = (int*)alloc((size_t)N * 4);
  int*      csr    = (int*)alloc((size_t)E * 4);
  float*    mean   = (float*)alloc((size_t)N * C * 4);
  float*    hA     = (float*)alloc((size_t)N * C * 4);
  float*    hB     = (float*)alloc((size_t)N * C * 4);
  float*    B1     = (float*)alloc((size_t)2 * C * C * 4);
  float*    B2     = (float*)alloc((size_t)2 * C * C * 4);
  float*    B3     = (float*)alloc((size_t)2 * C * C * 4);
  unsigned* pooled = (unsigned*)alloc((size_t)NGRAPH * C * 4);

  hipMemsetAsync(deg, 0, (size_t)N * 4, stream);
  hipMemsetAsync(cursor, 0, (size_t)N * 4, stream);
  hipMemsetAsync(pooled, 0, (size_t)NGRAPH * C * 4, stream);

  deg_kernel<<<(E + 255) / 256, 256, 0, stream>>>(dstv, deg, E);
  inv_kernel<<<(N + 255) / 256, 256, 0, stream>>>(deg, inv_d, N);
  scan_kernel<<<1, 1024, 0, stream>>>(deg, rows, N);
  csr_fill_kernel<<<(E + 255) / 256, 256, 0, stream>>>(srcv, dstv, rows, cursor, csr, E);

  pack_kernel<<<(2 * C * C + 255) / 256, 256, 0, stream>>>(W1l, W1r, B1);
  pack_kernel<<<(2 * C * C + 255) / 256, 256, 0, stream>>>(W2l, W2r, B2);
  pack_kernel<<<(2 * C * C + 255) / 256, 256, 0, stream>>>(W3l, W3r, B3);

  dim3 ggrid(C / BN, (N + BM - 1) / BM);
  int aggblocks = (N + 3) / 4;   // 4 nodes (waves) per 256-thread block

  // layer 1
  agg_csr_kernel<<<aggblocks, 256, 0, stream>>>(x, csr, rows, inv_d, mean, N);
  gemm_fused<<<ggrid, 256, 0, stream>>>(mean, x, B1, b1, hA, N);
  // layer 2
  agg_csr_kernel<<<aggblocks, 256, 0, stream>>>(hA, csr, rows, inv_d, mean, N);
  gemm_fused<<<ggrid, 256, 0, stream>>>(mean, hA, B2, b2, hB, N);
  // layer 3
  agg_csr_kernel<<<aggblocks, 256, 0, stream>>>(hB, csr, rows, inv_d, mean, N);
  gemm_fused<<<ggrid, 256, 0, stream>>>(mean, hB, B3, b3, hA, N);

  pool_kernel<<<(N + 255) / 256, 128, 0, stream>>>(hA, batch, pooled, N);
  fc_kernel<<<1, 128, 0, stream>>>(pooled, Wfc, bfc, out);
}

// Round 3
// 476.437 us; speedup vs baseline: 7.2202x; 1.3618x over previous
//
#include <hip/hip_runtime.h>
#include <hip/hip_bf16.h>

#define NEG_SLOPE 0.01f
#define C 128
#define NGRAPH 64

typedef short short8 __attribute__((ext_vector_type(8)));
typedef float f32x4 __attribute__((ext_vector_type(4)));

// monotone float <-> uint mapping for atomicMax-based segment max
__device__ __forceinline__ unsigned fmap(float x){
  unsigned b = __float_as_uint(x);
  return (b & 0x80000000u) ? ~b : (b | 0x80000000u);
}
__device__ __forceinline__ float funmap(unsigned k){
  return (k & 0x80000000u) ? __uint_as_float(k & 0x7FFFFFFFu) : __uint_as_float(~k);
}

// split fp32 into bf16 hi (truncate) + bf16 lo (residual); a ~= hi + lo, err ~2^-16
__device__ __forceinline__ void split_bf16(float a, unsigned short& hi, unsigned short& lo){
  unsigned u = __float_as_uint(a);
  hi = (unsigned short)(u >> 16);
  float r = a - __uint_as_float(u & 0xFFFF0000u);
  lo = (unsigned short)(__float_as_uint(r) >> 16);
}

// ---------- CSR build ----------
__global__ void deg_kernel(const int* __restrict__ dst, int* __restrict__ deg, int E){
  int e = blockIdx.x * blockDim.x + threadIdx.x;
  if(e < E) atomicAdd(&deg[dst[e]], 1);
}

__global__ void inv_kernel(const int* __restrict__ deg, float* __restrict__ inv_deg, int N){
  int n = blockIdx.x * blockDim.x + threadIdx.x;
  if(n < N) inv_deg[n] = 1.0f / fmaxf((float)deg[n], 1.0f);
}

// multi-block scan, step 1: per-block inclusive scan + block sums
__global__ void scan_block(const int* __restrict__ deg, int* __restrict__ incl,
                           int* __restrict__ bsum, int N){
  __shared__ int sm[1024];
  int t = threadIdx.x;
  int i = blockIdx.x * 1024 + t;
  int v = (i < N) ? deg[i] : 0;
  sm[t] = v;
  __syncthreads();
  for(int off = 1; off < 1024; off <<= 1){
    int a = (t >= off) ? sm[t - off] : 0;
    __syncthreads();
    sm[t] += a;
    __syncthreads();
  }
  if(i < N) incl[i] = sm[t];
  if(t == 1023) bsum[blockIdx.x] = sm[t];
}

// step 2: exclusive scan of block sums (nb <= 64, one wave)
__global__ void scan_bsum(const int* __restrict__ bsum, int* __restrict__ boff, int nb){
  __shared__ int sm[64];
  int t = threadIdx.x;
  sm[t] = (t < nb) ? bsum[t] : 0;
  __syncthreads();
  for(int off = 1; off < 64; off <<= 1){
    int a = (t >= off) ? sm[t - off] : 0;
    __syncthreads();
    sm[t] += a;
    __syncthreads();
  }
  if(t < nb) boff[t] = sm[t] - bsum[t];
}

// step 3: rows[i] = exclusive prefix = incl[i] - deg[i] + boff[block]
__global__ void finalize_rows(const int* __restrict__ incl, const int* __restrict__ deg,
                              const int* __restrict__ boff, int* __restrict__ rows,
                              int N, int E){
  int i = blockIdx.x * blockDim.x + threadIdx.x;
  if(i < N) rows[i] = incl[i] - deg[i] + boff[i >> 10];
  if(i == 0) rows[N] = E;
}

__global__ void csr_fill_kernel(const int* __restrict__ src, const int* __restrict__ dst,
                                const int* __restrict__ row_start, int* __restrict__ cursor,
                                int* __restrict__ csr, int E){
  int e = blockIdx.x * blockDim.x + threadIdx.x;
  if(e >= E) return;
  int d = dst[e];
  int p = atomicAdd(&cursor[d], 1);
  csr[row_start[d] + p] = src[e];
}

// ---------- aggregation: one wave per node, CSR gather-sum, write mean ----------
__global__ __launch_bounds__(256) void agg_csr_kernel(
    const float* __restrict__ xin, const int* __restrict__ csr,
    const int* __restrict__ row_start, const float* __restrict__ inv_deg,
    float* __restrict__ mean, int N)
{
  int node = blockIdx.x * (blockDim.x >> 6) + (threadIdx.x >> 6);
  if(node >= N) return;
  int lane = threadIdx.x & 63;
  int beg = row_start[node], end = row_start[node + 1];
  float2 acc = make_float2(0.f, 0.f);
  for(int base = beg; base < end; base += 64){
    int cnt = end - base; if(cnt > 64) cnt = 64;
    int s_l = (base + lane < end) ? csr[base + lane] : 0;
    for(int j = 0; j < cnt; j++){
      int s = __shfl(s_l, j, 64);
      float2 v = *(const float2*)(xin + (long long)s * C + lane * 2);
      acc.x += v.x; acc.y += v.y;
    }
  }
  float sc = inv_deg[node];
  *(float2*)(mean + (long long)node * C + lane * 2) = make_float2(acc.x * sc, acc.y * sc);
}

// ---------- weight pre-pack into MFMA B-fragment layout, bf16 hi/lo ----------
// B = [W_l ; W_r] (256 x 128).  frag index: (((kstep*4 + kg)*128 + n)*8 + j)
// where k = kstep*32 + kg*8 + j.  hi at [0 .. 32767], lo at [32768 ..].
__global__ void pack_kernel(const float* __restrict__ Wl, const float* __restrict__ Wr,
                            short* __restrict__ Bpk){
  int idx = blockIdx.x * blockDim.x + threadIdx.x;   // 0 .. 32767
  if(idx >= 2 * C * C) return;
  int k = idx >> 7, n = idx & 127;
  float w = (k < C) ? Wl[k * C + n] : Wr[(k - C) * C + n];
  unsigned short hi, lo;
  split_bf16(w, hi, lo);
  int kstep = k >> 5, kg = (k >> 3) & 3, j = k & 7;
  int pos = ((kstep * 4 + kg) * C + n) * 8 + j;
  Bpk[pos] = (short)hi;
  Bpk[pos + 32768] = (short)lo;
}

// ---------- MFMA GEMM: h = leakyrelu([mean | x] @ B + bias) ----------
// A: [M,256] virtual fp32, split to bf16 hi/lo in-register.
// 3 MFMA passes: Ahi*Bhi + Alo*Bhi + Ahi*Blo  (~fp32 accuracy).
// Block: 128 rows x all 128 cols. 4 waves as 2x2 (wm, wn), wave tile 64x64.
__global__ __launch_bounds__(256) void gemm_mfma(
    const float* __restrict__ mean, const float* __restrict__ xin,
    const short* __restrict__ Bpk, const float* __restrict__ bias,
    float* __restrict__ hout, int M)
{
  // A staging in fragment-friendly layout: As[(kg*128 + m)*12 + j] (j=0..7, +4 pad)
  __shared__ float As[4 * 128 * 12];
  int tid = threadIdx.x;
  int bm = blockIdx.x * 128;
  int lane = tid & 63;
  int wave = tid >> 6;
  int wm = wave >> 1, wn = wave & 1;
  int lg = lane >> 4;        // k-group (0..3) for A/B frags, row-group for C/D
  int lm = lane & 15;        // m (A) / n (B) / col (C/D) within 16

  f32x4 acc[4][4];
#pragma unroll
  for(int i = 0; i < 4; i++)
#pragma unroll
    for(int j = 0; j < 4; j++)
      acc[i][j] = (f32x4){0.f, 0.f, 0.f, 0.f};

  const int r = tid >> 1;        // staging row 0..127
  const int half = tid & 1;      // which 16-k half of the 32-k step

  for(int ks = 0; ks < 8; ks++){
    // ---- stage A tile (128 x 32 fp32), coalesced 64B per thread ----
    const float* Abase = (ks < 4) ? mean : xin;
    int kcol = (ks & 3) * 32 + half * 16;
    int grow = bm + r;
    float4 v0, v1, v2, v3;
    if(grow < M){
      const float* p = Abase + (long long)grow * C + kcol;
      v0 = *(const float4*)(p + 0);
      v1 = *(const float4*)(p + 4);
      v2 = *(const float4*)(p + 8);
      v3 = *(const float4*)(p + 12);
    }else{
      v0 = v1 = v2 = v3 = make_float4(0.f, 0.f, 0.f, 0.f);
    }
    __syncthreads();   // previous iteration's reads done before overwrite
    int kg0 = half * 2;
    *(float4*)&As[((kg0    ) * 128 + r) * 12 + 0] = v0;
    *(float4*)&As[((kg0    ) * 128 + r) * 12 + 4] = v1;
    *(float4*)&As[((kg0 + 1) * 128 + r) * 12 + 0] = v2;
    *(float4*)&As[((kg0 + 1) * 128 + r) * 12 + 4] = v3;
    __syncthreads();

    // ---- B fragments straight from L2 (pre-packed layout) ----
    short8 bh[4], bl[4];
#pragma unroll
    for(int j = 0; j < 4; j++){
      const short* bp = Bpk + (((ks * 4 + lg) * C) + wn * 64 + j * 16 + lm) * 8;
      bh[j] = *(const short8*)bp;
      bl[j] = *(const short8*)(bp + 32768);
    }

    // ---- A fragments from LDS, split hi/lo ----
    short8 ah[4], al[4];
#pragma unroll
    for(int i = 0; i < 4; i++){
      int m = wm * 64 + i * 16 + lm;
      const float* ap = &As[(lg * 128 + m) * 12];
      float4 x0 = *(const float4*)ap;
      float4 x1 = *(const float4*)(ap + 4);
      unsigned short h, l;
      split_bf16(x0.x, h, l); ah[i][0] = h; al[i][0] = l;
      split_bf16(x0.y, h, l); ah[i][1] = h; al[i][1] = l;
      split_bf16(x0.z, h, l); ah[i][2] = h; al[i][2] = l;
      split_bf16(x0.w, h, l); ah[i][3] = h; al[i][3] = l;
      split_bf16(x1.x, h, l); ah[i][4] = h; al[i][4] = l;
      split_bf16(x1.y, h, l); ah[i][5] = h; al[i][5] = l;
      split_bf16(x1.z, h, l); ah[i][6] = h; al[i][6] = l;
      split_bf16(x1.w, h, l); ah[i][7] = h; al[i][7] = l;
    }

    // ---- MFMA ----
#pragma unroll
    for(int i = 0; i < 4; i++)
#pragma unroll
      for(int j = 0; j < 4; j++){
        acc[i][j] = __builtin_amdgcn_mfma_f32_16x16x32_bf16(ah[i], bh[j], acc[i][j], 0, 0, 0);
        acc[i][j] = __builtin_amdgcn_mfma_f32_16x16x32_bf16(al[i], bh[j], acc[i][j], 0, 0, 0);
        acc[i][j] = __builtin_amdgcn_mfma_f32_16x16x32_bf16(ah[i], bl[j], acc[i][j], 0, 0, 0);
      }
  }

  // ---- epilogue: C/D layout col=lane&15, row=(lane>>4)*4+reg ----
#pragma unroll
  for(int j = 0; j < 4; j++){
    int col = wn * 64 + j * 16 + lm;
    float bv = bias[col];
#pragma unroll
    for(int i = 0; i < 4; i++){
#pragma unroll
      for(int reg = 0; reg < 4; reg++){
        int row = bm + wm * 64 + i * 16 + lg * 4 + reg;
        if(row < M){
          float v = acc[i][j][reg] + bv;
          v = v > 0.f ? v : NEG_SLOPE * v;
          hout[(long long)row * C + col] = v;
        }
      }
    }
  }
}

// batch is sorted: run local max per contiguous graph segment, flush with atomicMax
__global__ void pool_kernel(const float* __restrict__ h, const int* __restrict__ batch,
                            unsigned* __restrict__ pooled_u, int N){
  int f = threadIdx.x;            // 0..127 (feature)
  int n0 = blockIdx.x * 256;      // node tile
  int cur_g = -1;
  unsigned run = 0u;
  for(int i = 0; i < 256; i++){
    int n = n0 + i;
    if(n >= N) break;
    int g = batch[n];
    if(g != cur_g){
      if(cur_g >= 0) atomicMax(&pooled_u[cur_g * C + f], run);
      cur_g = g; run = 0u;
    }
    unsigned k = fmap(h[(long long)n * C + f]);
    run = run > k ? run : k;
  }
  if(cur_g >= 0) atomicMax(&pooled_u[cur_g * C + f], run);
}

__global__ void fc_kernel(const unsigned* __restrict__ pooled_u, const float* __restrict__ Wfc,
                          const float* __restrict__ bfc, float* __restrict__ out){
  int t = threadIdx.x;   // 0..127
  int g = t >> 1, o = t & 1;
  float s = bfc[o];
  for(int k = 0; k < C; k++)
    s += funmap(pooled_u[g * C + k]) * Wfc[k * 2 + o];
  out[g * 2 + o] = s;
}

extern "C" void kernel_launch(void* const* d_in, const int* in_sizes, int n_in,
                              void* d_out, int out_size, void* d_ws, size_t ws_size,
                              hipStream_t stream) {
  const float* x    = (const float*)d_in[0];
  const int*   ei   = (const int*)d_in[1];
  const int*   batch= (const int*)d_in[2];
  const float* W1l  = (const float*)d_in[3];
  const float* b1   = (const float*)d_in[4];
  const float* W1r  = (const float*)d_in[5];
  const float* W2l  = (const float*)d_in[6];
  const float* b2   = (const float*)d_in[7];
  const float* W2r  = (const float*)d_in[8];
  const float* W3l  = (const float*)d_in[9];
  const float* b3   = (const float*)d_in[10];
  const float* W3r  = (const float*)d_in[11];
  const float* Wfc  = (const float*)d_in[12];
  const float* bfc  = (const float*)d_in[13];
  float* out = (float*)d_out;

  const int N = in_sizes[0] / C;   // 50000
  const int E = in_sizes[1] / 2;   // 600000
  const int* srcv = ei;
  const int* dstv = ei + E;

  char* ws = (char*)d_ws;
  size_t off = 0;
  auto alloc = [&](size_t bytes) -> void* {
    void* p = ws + off;
    off += (bytes + 255) & ~(size_t)255;
    return p;
  };
  int*      deg    = (int*)alloc((size_t)N * 4);
  float*    inv_d  = (float*)alloc((size_t)N * 4);
  int*      incl   = (int*)alloc((size_t)N * 4);
  int*      bsum   = (int*)alloc((size_t)64 * 4);
  int*      boff   = (int*)alloc((size_t)64 * 4);
  int*      rows   = (int*)alloc((size_t)(N + 1) * 4);
  int*      cursor = (int*)alloc((size_t)N * 4);
  int*      csr    = (int*)alloc((size_t)E * 4);
  float*    mean   = (float*)alloc((size_t)N * C * 4);
  float*    hA     = (float*)alloc((size_t)N * C * 4);
  float*    hB     = (float*)alloc((size_t)N * C * 4);
  short*    B1     = (short*)alloc((size_t)2 * 2 * C * C * 2);
  short*    B2     = (short*)alloc((size_t)2 * 2 * C * C * 2);
  short*    B3     = (short*)alloc((size_t)2 * 2 * C * C * 2);
  unsigned* pooled = (unsigned*)alloc((size_t)NGRAPH * C * 4);

  hipMemsetAsync(deg, 0, (size_t)N * 4, stream);
  hipMemsetAsync(cursor, 0, (size_t)N * 4, stream);
  hipMemsetAsync(pooled, 0, (size_t)NGRAPH * C * 4, stream);

  const int nb = (N + 1023) / 1024;   // 49
  deg_kernel<<<(E + 255) / 256, 256, 0, stream>>>(dstv, deg, E);
  inv_kernel<<<(N + 255) / 256, 256, 0, stream>>>(deg, inv_d, N);
  scan_block<<<nb, 1024, 0, stream>>>(deg, incl, bsum, N);
  scan_bsum<<<1, 64, 0, stream>>>(bsum, boff, nb);
  finalize_rows<<<(N + 255) / 256, 256, 0, stream>>>(incl, deg, boff, rows, N, E);
  csr_fill_kernel<<<(E + 255) / 256, 256, 0, stream>>>(srcv, dstv, rows, cursor, csr, E);

  pack_kernel<<<(2 * C * C + 255) / 256, 256, 0, stream>>>(W1l, W1r, B1);
  pack_kernel<<<(2 * C * C + 255) / 256, 256, 0, stream>>>(W2l, W2r, B2);
  pack_kernel<<<(2 * C * C + 255) / 256, 256, 0, stream>>>(W3l, W3r, B3);

  int gemmblocks = (N + 127) / 128;
  int aggblocks = (N + 3) / 4;   // 4 nodes (waves) per 256-thread block

  // layer 1
  agg_csr_kernel<<<aggblocks, 256, 0, stream>>>(x, csr, rows, inv_d, mean, N);
  gemm_mfma<<<gemmblocks, 256, 0, stream>>>(mean, x, B1, b1, hA, N);
  // layer 2
  agg_csr_kernel<<<aggblocks, 256, 0, stream>>>(hA, csr, rows, inv_d, mean, N);
  gemm_mfma<<<gemmblocks, 256, 0, stream>>>(mean, hA, B2, b2, hB, N);
  // layer 3
  agg_csr_kernel<<<aggblocks, 256, 0, stream>>>(hB, csr, rows, inv_d, mean, N);
  gemm_mfma<<<gemmblocks, 256, 0, stream>>>(mean, hB, B3, b3, hA, N);

  pool_kernel<<<(N + 255) / 256, 128, 0, stream>>>(hA, batch, pooled, N);
  fc_kernel<<<1, 128, 0, stream>>>(pooled, Wfc, bfc, out);
}

// Round 4
// 412.419 us; speedup vs baseline: 8.3409x; 1.1552x over previous
//
#include <hip/hip_runtime.h>
#include <hip/hip_bf16.h>

#define NEG_SLOPE 0.01f
#define C 128
#define NGRAPH 64

typedef short short8 __attribute__((ext_vector_type(8)));
typedef float f32x4 __attribute__((ext_vector_type(4)));

// monotone float <-> uint mapping for atomicMax-based segment max
__device__ __forceinline__ unsigned fmap(float x){
  unsigned b = __float_as_uint(x);
  return (b & 0x80000000u) ? ~b : (b | 0x80000000u);
}
__device__ __forceinline__ float funmap(unsigned k){
  return (k & 0x80000000u) ? __uint_as_float(k & 0x7FFFFFFFu) : __uint_as_float(~k);
}

// split fp32 into bf16 hi (truncate) + bf16 lo (residual); a ~= hi + lo, err ~2^-16
__device__ __forceinline__ void split_bf16(float a, unsigned short& hi, unsigned short& lo){
  unsigned u = __float_as_uint(a);
  hi = (unsigned short)(u >> 16);
  float r = a - __uint_as_float(u & 0xFFFF0000u);
  lo = (unsigned short)(__float_as_uint(r) >> 16);
}

// ---------- CSR build ----------
__global__ void deg_kernel(const int* __restrict__ dst, int* __restrict__ deg, int E){
  int e = blockIdx.x * blockDim.x + threadIdx.x;
  if(e < E) atomicAdd(&deg[dst[e]], 1);
}

__global__ void inv_kernel(const int* __restrict__ deg, float* __restrict__ inv_deg, int N){
  int n = blockIdx.x * blockDim.x + threadIdx.x;
  if(n < N) inv_deg[n] = 1.0f / fmaxf((float)deg[n], 1.0f);
}

// multi-block scan, step 1: per-block inclusive scan + block sums
__global__ void scan_block(const int* __restrict__ deg, int* __restrict__ incl,
                           int* __restrict__ bsum, int N){
  __shared__ int sm[1024];
  int t = threadIdx.x;
  int i = blockIdx.x * 1024 + t;
  int v = (i < N) ? deg[i] : 0;
  sm[t] = v;
  __syncthreads();
  for(int off = 1; off < 1024; off <<= 1){
    int a = (t >= off) ? sm[t - off] : 0;
    __syncthreads();
    sm[t] += a;
    __syncthreads();
  }
  if(i < N) incl[i] = sm[t];
  if(t == 1023) bsum[blockIdx.x] = sm[t];
}

// step 2: exclusive scan of block sums (nb <= 64, one wave)
__global__ void scan_bsum(const int* __restrict__ bsum, int* __restrict__ boff, int nb){
  __shared__ int sm[64];
  int t = threadIdx.x;
  sm[t] = (t < nb) ? bsum[t] : 0;
  __syncthreads();
  for(int off = 1; off < 64; off <<= 1){
    int a = (t >= off) ? sm[t - off] : 0;
    __syncthreads();
    sm[t] += a;
    __syncthreads();
  }
  if(t < nb) boff[t] = sm[t] - bsum[t];
}

// step 3: rows[i] = exclusive prefix = incl[i] - deg[i] + boff[block]
__global__ void finalize_rows(const int* __restrict__ incl, const int* __restrict__ deg,
                              const int* __restrict__ boff, int* __restrict__ rows,
                              int N, int E){
  int i = blockIdx.x * blockDim.x + threadIdx.x;
  if(i < N) rows[i] = incl[i] - deg[i] + boff[i >> 10];
  if(i == 0) rows[N] = E;
}

__global__ void csr_fill_kernel(const int* __restrict__ src, const int* __restrict__ dst,
                                const int* __restrict__ row_start, int* __restrict__ cursor,
                                int* __restrict__ csr, int E){
  int e = blockIdx.x * blockDim.x + threadIdx.x;
  if(e >= E) return;
  int d = dst[e];
  int p = atomicAdd(&cursor[d], 1);
  csr[row_start[d] + p] = src[e];
}

// ---------- aggregation: one wave per node, CSR gather-sum, write mean ----------
__global__ __launch_bounds__(256) void agg_csr_kernel(
    const float* __restrict__ xin, const int* __restrict__ csr,
    const int* __restrict__ row_start, const float* __restrict__ inv_deg,
    float* __restrict__ mean, int N)
{
  int node = blockIdx.x * (blockDim.x >> 6) + (threadIdx.x >> 6);
  if(node >= N) return;
  int lane = threadIdx.x & 63;
  int beg = row_start[node], end = row_start[node + 1];
  float2 acc = make_float2(0.f, 0.f);
  for(int base = beg; base < end; base += 64){
    int cnt = end - base; if(cnt > 64) cnt = 64;
    int s_l = (base + lane < end) ? csr[base + lane] : 0;
    for(int j = 0; j < cnt; j++){
      int s = __shfl(s_l, j, 64);
      float2 v = *(const float2*)(xin + (long long)s * C + lane * 2);
      acc.x += v.x; acc.y += v.y;
    }
  }
  float sc = inv_deg[node];
  *(float2*)(mean + (long long)node * C + lane * 2) = make_float2(acc.x * sc, acc.y * sc);
}

// ---------- weight pre-pack into MFMA B-fragment layout, bf16 hi/lo ----------
// B = [W_l ; W_r] (256 x 128).  frag index: (((kstep*4 + kg)*128 + n)*8 + j)
// where k = kstep*32 + kg*8 + j.  hi at [0 .. 32767], lo at [32768 ..].
__global__ void pack_kernel(const float* __restrict__ Wl, const float* __restrict__ Wr,
                            short* __restrict__ Bpk){
  int idx = blockIdx.x * blockDim.x + threadIdx.x;   // 0 .. 32767
  if(idx >= 2 * C * C) return;
  int k = idx >> 7, n = idx & 127;
  float w = (k < C) ? Wl[k * C + n] : Wr[(k - C) * C + n];
  unsigned short hi, lo;
  split_bf16(w, hi, lo);
  int kstep = k >> 5, kg = (k >> 3) & 3, j = k & 7;
  int pos = ((kstep * 4 + kg) * C + n) * 8 + j;
  Bpk[pos] = (short)hi;
  Bpk[pos + 32768] = (short)lo;
}

// ---------- MFMA GEMM: h = leakyrelu([mean | x] @ B + bias) ----------
// A: [M,256] virtual fp32, split to bf16 hi/lo in-register.
// 3 MFMA passes: Ahi*Bhi + Alo*Bhi + Ahi*Blo  (~fp32 accuracy).
// Block: 128 rows x all 128 cols. 4 waves as 2x2 (wm, wn), wave tile 64x64.
// If pooled != nullptr (last layer): skip the store, fuse global-max-pool via
// atomicMax on monotone-uint-mapped values (hout unused in that case).
__global__ __launch_bounds__(256) void gemm_mfma(
    const float* __restrict__ mean, const float* __restrict__ xin,
    const short* __restrict__ Bpk, const float* __restrict__ bias,
    float* __restrict__ hout, int M,
    const int* __restrict__ batch, unsigned* __restrict__ pooled)
{
  // A staging in fragment-friendly layout: As[(kg*128 + m)*12 + j] (j=0..7, +4 pad)
  __shared__ float As[4 * 128 * 12];
  int tid = threadIdx.x;
  int bm = blockIdx.x * 128;
  int lane = tid & 63;
  int wave = tid >> 6;
  int wm = wave >> 1, wn = wave & 1;
  int lg = lane >> 4;        // k-group (0..3) for A/B frags, row-group for C/D
  int lm = lane & 15;        // m (A) / n (B) / col (C/D) within 16

  f32x4 acc[4][4];
#pragma unroll
  for(int i = 0; i < 4; i++)
#pragma unroll
    for(int j = 0; j < 4; j++)
      acc[i][j] = (f32x4){0.f, 0.f, 0.f, 0.f};

  const int r = tid >> 1;        // staging row 0..127
  const int half = tid & 1;      // which 16-k half of the 32-k step

  for(int ks = 0; ks < 8; ks++){
    // ---- stage A tile (128 x 32 fp32), coalesced 64B per thread ----
    const float* Abase = (ks < 4) ? mean : xin;
    int kcol = (ks & 3) * 32 + half * 16;
    int grow = bm + r;
    float4 v0, v1, v2, v3;
    if(grow < M){
      const float* p = Abase + (long long)grow * C + kcol;
      v0 = *(const float4*)(p + 0);
      v1 = *(const float4*)(p + 4);
      v2 = *(const float4*)(p + 8);
      v3 = *(const float4*)(p + 12);
    }else{
      v0 = v1 = v2 = v3 = make_float4(0.f, 0.f, 0.f, 0.f);
    }
    __syncthreads();   // previous iteration's reads done before overwrite
    int kg0 = half * 2;
    *(float4*)&As[((kg0    ) * 128 + r) * 12 + 0] = v0;
    *(float4*)&As[((kg0    ) * 128 + r) * 12 + 4] = v1;
    *(float4*)&As[((kg0 + 1) * 128 + r) * 12 + 0] = v2;
    *(float4*)&As[((kg0 + 1) * 128 + r) * 12 + 4] = v3;
    __syncthreads();

    // ---- B fragments straight from L2 (pre-packed layout) ----
    short8 bh[4], bl[4];
#pragma unroll
    for(int j = 0; j < 4; j++){
      const short* bp = Bpk + (((ks * 4 + lg) * C) + wn * 64 + j * 16 + lm) * 8;
      bh[j] = *(const short8*)bp;
      bl[j] = *(const short8*)(bp + 32768);
    }

    // ---- A fragments from LDS, split hi/lo ----
    short8 ah[4], al[4];
#pragma unroll
    for(int i = 0; i < 4; i++){
      int m = wm * 64 + i * 16 + lm;
      const float* ap = &As[(lg * 128 + m) * 12];
      float4 x0 = *(const float4*)ap;
      float4 x1 = *(const float4*)(ap + 4);
      unsigned short h, l;
      split_bf16(x0.x, h, l); ah[i][0] = h; al[i][0] = l;
      split_bf16(x0.y, h, l); ah[i][1] = h; al[i][1] = l;
      split_bf16(x0.z, h, l); ah[i][2] = h; al[i][2] = l;
      split_bf16(x0.w, h, l); ah[i][3] = h; al[i][3] = l;
      split_bf16(x1.x, h, l); ah[i][4] = h; al[i][4] = l;
      split_bf16(x1.y, h, l); ah[i][5] = h; al[i][5] = l;
      split_bf16(x1.z, h, l); ah[i][6] = h; al[i][6] = l;
      split_bf16(x1.w, h, l); ah[i][7] = h; al[i][7] = l;
    }

    // ---- MFMA ----
#pragma unroll
    for(int i = 0; i < 4; i++)
#pragma unroll
      for(int j = 0; j < 4; j++){
        acc[i][j] = __builtin_amdgcn_mfma_f32_16x16x32_bf16(ah[i], bh[j], acc[i][j], 0, 0, 0);
        acc[i][j] = __builtin_amdgcn_mfma_f32_16x16x32_bf16(al[i], bh[j], acc[i][j], 0, 0, 0);
        acc[i][j] = __builtin_amdgcn_mfma_f32_16x16x32_bf16(ah[i], bl[j], acc[i][j], 0, 0, 0);
      }
  }

  // ---- epilogue: C/D layout col=lane&15, row=(lane>>4)*4+reg ----
  if(pooled == nullptr){
#pragma unroll
    for(int j = 0; j < 4; j++){
      int col = wn * 64 + j * 16 + lm;
      float bv = bias[col];
#pragma unroll
      for(int i = 0; i < 4; i++){
#pragma unroll
        for(int reg = 0; reg < 4; reg++){
          int row = bm + wm * 64 + i * 16 + lg * 4 + reg;
          if(row < M){
            float v = acc[i][j][reg] + bv;
            v = v > 0.f ? v : NEG_SLOPE * v;
            hout[(long long)row * C + col] = v;
          }
        }
      }
    }
  }else{
    // fused global-max-pool: reg-quad covers 4 consecutive rows
#pragma unroll
    for(int i = 0; i < 4; i++){
      int row0 = bm + wm * 64 + i * 16 + lg * 4;
      if(row0 >= M) continue;
      bool whole = (row0 + 3 < M);
      int g0 = batch[row0];
      bool same = whole && (batch[row0 + 3] == g0);
#pragma unroll
      for(int j = 0; j < 4; j++){
        int col = wn * 64 + j * 16 + lm;
        float bv = bias[col];
        float v0 = acc[i][j][0] + bv; v0 = v0 > 0.f ? v0 : NEG_SLOPE * v0;
        float v1 = acc[i][j][1] + bv; v1 = v1 > 0.f ? v1 : NEG_SLOPE * v1;
        float v2 = acc[i][j][2] + bv; v2 = v2 > 0.f ? v2 : NEG_SLOPE * v2;
        float v3 = acc[i][j][3] + bv; v3 = v3 > 0.f ? v3 : NEG_SLOPE * v3;
        if(same){
          float m01 = fmaxf(v0, v1), m23 = fmaxf(v2, v3);
          atomicMax(&pooled[g0 * C + col], fmap(fmaxf(m01, m23)));
        }else{
          float vv[4] = {v0, v1, v2, v3};
#pragma unroll
          for(int reg = 0; reg < 4; reg++){
            int row = row0 + reg;
            if(row < M) atomicMax(&pooled[batch[row] * C + col], fmap(vv[reg]));
          }
        }
      }
    }
  }
}

__global__ void fc_kernel(const unsigned* __restrict__ pooled_u, const float* __restrict__ Wfc,
                          const float* __restrict__ bfc, float* __restrict__ out){
  int t = threadIdx.x;   // 0..127
  int g = t >> 1, o = t & 1;
  float s = bfc[o];
  for(int k = 0; k < C; k++)
    s += funmap(pooled_u[g * C + k]) * Wfc[k * 2 + o];
  out[g * 2 + o] = s;
}

extern "C" void kernel_launch(void* const* d_in, const int* in_sizes, int n_in,
                              void* d_out, int out_size, void* d_ws, size_t ws_size,
                              hipStream_t stream) {
  const float* x    = (const float*)d_in[0];
  const int*   ei   = (const int*)d_in[1];
  const int*   batch= (const int*)d_in[2];
  const float* W1l  = (const float*)d_in[3];
  const float* b1   = (const float*)d_in[4];
  const float* W1r  = (const float*)d_in[5];
  const float* W2l  = (const float*)d_in[6];
  const float* b2   = (const float*)d_in[7];
  const float* W2r  = (const float*)d_in[8];
  const float* W3l  = (const float*)d_in[9];
  const float* b3   = (const float*)d_in[10];
  const float* W3r  = (const float*)d_in[11];
  const float* Wfc  = (const float*)d_in[12];
  const float* bfc  = (const float*)d_in[13];
  float* out = (float*)d_out;

  const int N = in_sizes[0] / C;   // 50000
  const int E = in_sizes[1] / 2;   // 600000
  const int* srcv = ei;
  const int* dstv = ei + E;

  char* ws = (char*)d_ws;
  size_t off = 0;
  auto alloc = [&](size_t bytes) -> void* {
    void* p = ws + off;
    off += (bytes + 255) & ~(size_t)255;
    return p;
  };
  int*      deg    = (int*)alloc((size_t)N * 4);
  float*    inv_d  = (float*)alloc((size_t)N * 4);
  int*      incl   = (int*)alloc((size_t)N * 4);
  int*      bsum   = (int*)alloc((size_t)64 * 4);
  int*      boff   = (int*)alloc((size_t)64 * 4);
  int*      rows   = (int*)alloc((size_t)(N + 1) * 4);
  int*      cursor = (int*)alloc((size_t)N * 4);
  int*      csr    = (int*)alloc((size_t)E * 4);
  float*    mean   = (float*)alloc((size_t)N * C * 4);
  float*    hA     = (float*)alloc((size_t)N * C * 4);
  float*    hB     = (float*)alloc((size_t)N * C * 4);
  short*    B1     = (short*)alloc((size_t)2 * 2 * C * C * 2);
  short*    B2     = (short*)alloc((size_t)2 * 2 * C * C * 2);
  short*    B3     = (short*)alloc((size_t)2 * 2 * C * C * 2);
  unsigned* pooled = (unsigned*)alloc((size_t)NGRAPH * C * 4);

  hipMemsetAsync(deg, 0, (size_t)N * 4, stream);
  hipMemsetAsync(cursor, 0, (size_t)N * 4, stream);
  hipMemsetAsync(pooled, 0, (size_t)NGRAPH * C * 4, stream);

  const int nb = (N + 1023) / 1024;   // 49
  deg_kernel<<<(E + 255) / 256, 256, 0, stream>>>(dstv, deg, E);
  inv_kernel<<<(N + 255) / 256, 256, 0, stream>>>(deg, inv_d, N);
  scan_block<<<nb, 1024, 0, stream>>>(deg, incl, bsum, N);
  scan_bsum<<<1, 64, 0, stream>>>(bsum, boff, nb);
  finalize_rows<<<(N + 255) / 256, 256, 0, stream>>>(incl, deg, boff, rows, N, E);
  csr_fill_kernel<<<(E + 255) / 256, 256, 0, stream>>>(srcv, dstv, rows, cursor, csr, E);

  pack_kernel<<<(2 * C * C + 255) / 256, 256, 0, stream>>>(W1l, W1r, B1);
  pack_kernel<<<(2 * C * C + 255) / 256, 256, 0, stream>>>(W2l, W2r, B2);
  pack_kernel<<<(2 * C * C + 255) / 256, 256, 0, stream>>>(W3l, W3r, B3);

  int gemmblocks = (N + 127) / 128;
  int aggblocks = (N + 3) / 4;   // 4 nodes (waves) per 256-thread block

  // layer 1
  agg_csr_kernel<<<aggblocks, 256, 0, stream>>>(x, csr, rows, inv_d, mean, N);
  gemm_mfma<<<gemmblocks, 256, 0, stream>>>(mean, x, B1, b1, hA, N, nullptr, nullptr);
  // layer 2
  agg_csr_kernel<<<aggblocks, 256, 0, stream>>>(hA, csr, rows, inv_d, mean, N);
  gemm_mfma<<<gemmblocks, 256, 0, stream>>>(mean, hA, B2, b2, hB, N, nullptr, nullptr);
  // layer 3: fused global-max-pool epilogue (no hout store)
  agg_csr_kernel<<<aggblocks, 256, 0, stream>>>(hB, csr, rows, inv_d, mean, N);
  gemm_mfma<<<gemmblocks, 256, 0, stream>>>(mean, hB, B3, b3, hA, N, batch, pooled);

  fc_kernel<<<1, 128, 0, stream>>>(pooled, Wfc, bfc, out);
}